// Round 6
// baseline (601.545 us; speedup 1.0000x reference)
//
#include <hip/hip_runtime.h>
#include <stdint.h>

#define BATCH  65536
#define IN_DIM 1024
#define MASKED 512
#define HIDDEN 1024

typedef unsigned short u16;
typedef __bf16 bf16x8 __attribute__((ext_vector_type(8)));
typedef float  f32x4  __attribute__((ext_vector_type(4)));

typedef __attribute__((address_space(1))) void gvoid;
typedef __attribute__((address_space(3))) void lvoid;

#define WAITV(N) asm volatile("s_waitcnt vmcnt(" #N ")" ::: "memory")
#define WAITL0() asm volatile("s_waitcnt lgkmcnt(0)" ::: "memory")
#define FENCE()  asm volatile("" ::: "memory")

__device__ __forceinline__ u16 f32_to_bf16(float f) {
    union { float f; uint32_t u; } v; v.f = f;
    uint32_t r = v.u + 0x7FFFu + ((v.u >> 16) & 1u);   // round-to-nearest-even
    return (u16)(r >> 16);
}

// ---------------------------------------------------------------------------
// prep: x (BATCH x IN_DIM f32) -> xm (BATCH x MASKED bf16)  [even columns]
// ---------------------------------------------------------------------------
__global__ void prep_xm(const float* __restrict__ x, u16* __restrict__ xm) {
    int idx = blockIdx.x * blockDim.x + threadIdx.x;
    const float4* xv = reinterpret_cast<const float4*>(x);
    float4 v0 = xv[idx * 2];
    float4 v1 = xv[idx * 2 + 1];
    ushort4 o;
    o.x = f32_to_bf16(v0.x);
    o.y = f32_to_bf16(v0.z);
    o.z = f32_to_bf16(v1.x);
    o.w = f32_to_bf16(v1.z);
    reinterpret_cast<ushort4*>(xm)[idx] = o;
}

// ---------------------------------------------------------------------------
// weight convert+transpose: W (K x N f32, row-major) -> Wt (N x K bf16)
// ---------------------------------------------------------------------------
__global__ void wconv(const float* __restrict__ W, u16* __restrict__ Wt,
                      int K, int N) {
    __shared__ float t[32][33];
    const int nbk = K / 32;
    const int bk = blockIdx.x % nbk;
    const int bn = blockIdx.x / nbk;
    const int tx = threadIdx.x & 31;
    const int ty = threadIdx.x >> 5;
    const int k0 = bk * 32, n0 = bn * 32;
    #pragma unroll
    for (int i = 0; i < 4; ++i)
        t[ty + i * 8][tx] = W[(int64_t)(k0 + ty + i * 8) * N + n0 + tx];
    __syncthreads();
    #pragma unroll
    for (int i = 0; i < 4; ++i)
        Wt[(int64_t)(n0 + ty + i * 8) * K + k0 + tx] = f32_to_bf16(t[tx][ty + i * 8]);
}

// ---------------------------------------------------------------------------
// Fully fused coupling MLP. One block = 64 batch rows, 512 threads, 8 waves.
//
// LDS map (byte offsets, 152 KB total):
//   [0,      65536): XM  [64][512] bf16   (later overlaid by H2 low half)
//   [65536, 114688): RING12: 3 x 16 KB W-tile slots [256][32] bf16
//   [114688,147456): HQ  [64][256] bf16 (h1 quarter)   (dead before overlaps)
//   [0,     131072): H2  [64][1024] bf16 (overlay; XM+RING12 dead)
//   [131072,155648): RING3: 3 x 8 KB W3-tile slots [128][32] bf16
//
// Schedule: 192 flattened phases (per quarter q: 16 G1 phases + 32 G2 phases)
// sharing ONE 3-slot ring with counted vmcnt (2 loads/tile, WAITV(2)), then
// H2 pack, then 128 G3 phases on a second ring (1 load/tile, WAITV(1)).
// All LDS arrays XOR-swizzled (R4-proven involution class): DMA'd arrays get
// pre-swizzled GLOBAL source + matching XOR on ds_read; ds_write-produced
// arrays (HQ/H2) get the XOR on both write and read.
// ---------------------------------------------------------------------------
__global__ __launch_bounds__(512, 1)
void mlp_fused(const u16* __restrict__ xm,
               const u16* __restrict__ W1t, const u16* __restrict__ W2t,
               const u16* __restrict__ W3t,
               const float* __restrict__ b1, const float* __restrict__ b2,
               const float* __restrict__ b3,
               const float* __restrict__ X, float* __restrict__ Y) {
    __shared__ __align__(16) char pool[155648];
    u16* const XM = (u16*)pool;                 // [64][512]
    u16* const HQ = (u16*)(pool + 114688);      // [64][256]
    u16* const H2 = (u16*)pool;                 // [64][1024] overlay

    const int tid  = threadIdx.x;
    const int lane = tid & 63;
    const int w    = tid >> 6;                  // wave 0..7
    const int m0   = blockIdx.x * 64;

    const int cl    = lane & 15;
    const int rg    = (lane >> 4) * 4;
    const int klane = lane >> 4;                // 0..3
    const int sw7   = lane & 7;

    const int wm3 = w >> 2, wn3 = w & 3;        // G3 2Mx4N wave split

    // ---- stage helpers (uniform participation; counted-vmcnt safe) ----
    auto stage12 = [&](int pp) {                // 16KB tile, 2 loads/thread
        char* dstb = pool + 65536 + (pp % 3) * 16384;
        const int q2 = pp / 48;
        const int r2 = pp - q2 * 48;
        #pragma unroll
        for (int i = 0; i < 2; ++i) {
            const int c = i * 512 + tid;
            const int srow = c >> 2;
            const int scs  = ((c & 3) ^ ((srow + (srow >> 2)) & 3)) * 8;
            const u16* g;
            if (r2 < 16) {
                g = W1t + (q2 * 256 + srow) * 512 + r2 * 32 + scs;
            } else {
                const int rr2 = r2 - 16;
                g = W2t + ((rr2 >> 3) * 256 + srow) * 1024 + q2 * 256 + (rr2 & 7) * 32 + scs;
            }
            __builtin_amdgcn_global_load_lds((gvoid*)g, (lvoid*)(dstb + c * 16), 16, 0, 0);
        }
    };
    auto stage3 = [&](int pp) {                 // 8KB tile, 1 load/thread
        char* dstb = pool + 131072 + (pp % 3) * 8192;
        const int c = tid;
        const int srow = c >> 2;                // 0..127
        const int scs  = ((c & 3) ^ ((srow + (srow >> 2)) & 3)) * 8;
        const u16* g = W3t + ((pp >> 5) * 128 + srow) * 1024 + (pp & 31) * 32 + scs;
        __builtin_amdgcn_global_load_lds((gvoid*)g, (lvoid*)(dstb + c * 16), 16, 0, 0);
    };

    // ---- b1 preload (needed mid-ring; b2/b3 loaded later, between rings) ----
    float b1v[4][2];
    #pragma unroll
    for (int i = 0; i < 4; ++i)
        #pragma unroll
        for (int nf = 0; nf < 2; ++nf)
            b1v[i][nf] = b1[i * 256 + w * 32 + nf * 16 + cl];

    // ---- XM staging (pre-swizzled source) + ring prologue ----
    #pragma unroll
    for (int i = 0; i < 8; ++i) {
        const int c = i * 512 + tid;
        const int row = c >> 6, cc = c & 63;
        const u16* g = xm + (int64_t)(m0 + row) * 512 + ((cc ^ (row & 7)) * 8);
        __builtin_amdgcn_global_load_lds((gvoid*)g, (lvoid*)(pool + c * 16), 16, 0, 0);
    }
    stage12(0); stage12(1);
    WAITV(2);                      // b1 + XM + tile0 landed; tile1 in flight
    __builtin_amdgcn_s_barrier(); FENCE();

    f32x4 acc2[4][4][2];
    #pragma unroll
    for (int a = 0; a < 4; ++a)
        #pragma unroll
        for (int b = 0; b < 4; ++b)
            #pragma unroll
            for (int c = 0; c < 2; ++c)
                acc2[a][b][c] = f32x4{0.f, 0.f, 0.f, 0.f};

    // =================== G1 + G2 flattened ring (192 phases) ===============
    #pragma unroll
    for (int q = 0; q < 4; ++q) {
        // ---- G1 quarter: h1[:, q*256..+256), 16 phases ----
        f32x4 acc1[4][2];
        #pragma unroll
        for (int a = 0; a < 4; ++a)
            #pragma unroll
            for (int b = 0; b < 2; ++b)
                acc1[a][b] = f32x4{0.f, 0.f, 0.f, 0.f};

        for (int r = 0; r < 16; ++r) {
            const int p = q * 48 + r;
            const u16* sl = (const u16*)(pool + 65536 + (p % 3) * 16384);
            bf16x8 a[4], bb[2];
            #pragma unroll
            for (int mf = 0; mf < 4; ++mf)
                a[mf] = *(const bf16x8*)(XM + (cl + mf * 16) * 512 +
                                         (((r * 4 + klane) ^ sw7) * 8));
            #pragma unroll
            for (int nf = 0; nf < 2; ++nf) {
                const int row = w * 32 + nf * 16 + cl;
                bb[nf] = *(const bf16x8*)(sl + row * 32 +
                                          ((klane ^ ((row + (row >> 2)) & 3)) * 8));
            }
            if (p + 2 < 192) stage12(p + 2);
            __builtin_amdgcn_s_setprio(1);
            #pragma unroll
            for (int mf = 0; mf < 4; ++mf)
                #pragma unroll
                for (int nf = 0; nf < 2; ++nf)
                    acc1[mf][nf] = __builtin_amdgcn_mfma_f32_16x16x32_bf16(
                        a[mf], bb[nf], acc1[mf][nf], 0, 0, 0);
            __builtin_amdgcn_s_setprio(0);
            WAITL0(); __builtin_amdgcn_sched_barrier(0);
            if (p + 2 < 192) { WAITV(2); } else { WAITV(0); }
            __builtin_amdgcn_s_barrier(); FENCE();
        }

        // ---- pack Hq = relu(acc1 + b1) (write-side XOR swizzle) ----
        #pragma unroll
        for (int mf = 0; mf < 4; ++mf)
            #pragma unroll
            for (int nf = 0; nf < 2; ++nf) {
                const int nq = w * 32 + nf * 16 + cl;
                #pragma unroll
                for (int rr = 0; rr < 4; ++rr) {
                    const int m = mf * 16 + rg + rr;
                    float v = acc1[mf][nf][rr] + b1v[q][nf];
                    v = v > 0.f ? v : 0.f;
                    HQ[m * 256 + (((nq >> 3) ^ (m & 7)) * 8 + (nq & 7))] = f32_to_bf16(v);
                }
            }
        WAITL0();
        __builtin_amdgcn_s_barrier(); FENCE();

        // ---- G2 partial: acc2 += Hq @ W2[q-slice, :], 32 phases ----
        #pragma unroll
        for (int nc = 0; nc < 4; ++nc) {
            for (int kt2 = 0; kt2 < 8; ++kt2) {
                const int p = q * 48 + 16 + nc * 8 + kt2;
                const u16* sl = (const u16*)(pool + 65536 + (p % 3) * 16384);
                bf16x8 a[4], bb[2];
                #pragma unroll
                for (int mf = 0; mf < 4; ++mf)
                    a[mf] = *(const bf16x8*)(HQ + (cl + mf * 16) * 256 +
                                             (((kt2 * 4 + klane) ^ sw7) * 8));
                #pragma unroll
                for (int nf = 0; nf < 2; ++nf) {
                    const int row = w * 32 + nf * 16 + cl;
                    bb[nf] = *(const bf16x8*)(sl + row * 32 +
                                              ((klane ^ ((row + (row >> 2)) & 3)) * 8));
                }
                if (p + 2 < 192) stage12(p + 2);
                __builtin_amdgcn_s_setprio(1);
                #pragma unroll
                for (int mf = 0; mf < 4; ++mf)
                    #pragma unroll
                    for (int nf = 0; nf < 2; ++nf)
                        acc2[nc][mf][nf] = __builtin_amdgcn_mfma_f32_16x16x32_bf16(
                            a[mf], bb[nf], acc2[nc][mf][nf], 0, 0, 0);
                __builtin_amdgcn_s_setprio(0);
                WAITL0(); __builtin_amdgcn_sched_barrier(0);
                if (p + 2 < 192) { WAITV(2); } else { WAITV(0); }
                __builtin_amdgcn_s_barrier(); FENCE();
            }
        }
    }

    // =================== H2 pack (ring12 fully drained) ====================
    float b2v[4][2];
    #pragma unroll
    for (int i = 0; i < 4; ++i)
        #pragma unroll
        for (int nf = 0; nf < 2; ++nf)
            b2v[i][nf] = b2[i * 256 + w * 32 + nf * 16 + cl];
    WAITV(0);   // b2 landed; no DMA outstanding
    #pragma unroll
    for (int nc = 0; nc < 4; ++nc)
        #pragma unroll
        for (int mf = 0; mf < 4; ++mf)
            #pragma unroll
            for (int nf = 0; nf < 2; ++nf) {
                const int n2 = nc * 256 + w * 32 + nf * 16 + cl;
                #pragma unroll
                for (int rr = 0; rr < 4; ++rr) {
                    const int m = mf * 16 + rg + rr;
                    float v = acc2[nc][mf][nf][rr] + b2v[nc][nf];
                    v = v > 0.f ? v : 0.f;
                    H2[m * 1024 + (((n2 >> 3) ^ (m & 7)) * 8 + (n2 & 7))] = f32_to_bf16(v);
                }
            }
    WAITL0();
    __builtin_amdgcn_s_barrier(); FENCE();

    // =================== G3 ring (128 phases) ==============================
    float b3v[4][2];
    #pragma unroll
    for (int i = 0; i < 4; ++i)
        #pragma unroll
        for (int nf = 0; nf < 2; ++nf)
            b3v[i][nf] = b3[i * 128 + wn3 * 32 + nf * 16 + cl];
    stage3(0); stage3(1);
    WAITV(1);   // b3 + tile0 landed
    __builtin_amdgcn_s_barrier(); FENCE();

    f32x4 acc3[4][2][2];
    #pragma unroll
    for (int a = 0; a < 4; ++a)
        #pragma unroll
        for (int b = 0; b < 2; ++b)
            #pragma unroll
            for (int c = 0; c < 2; ++c)
                acc3[a][b][c] = f32x4{0.f, 0.f, 0.f, 0.f};

    #pragma unroll
    for (int nc3 = 0; nc3 < 4; ++nc3) {
        for (int kt3 = 0; kt3 < 32; ++kt3) {
            const int p3 = nc3 * 32 + kt3;
            const u16* sl3 = (const u16*)(pool + 131072 + (p3 % 3) * 8192);
            bf16x8 a3[2], bf3[2];
            #pragma unroll
            for (int mf = 0; mf < 2; ++mf)
                a3[mf] = *(const bf16x8*)(H2 + (wm3 * 32 + cl + mf * 16) * 1024 +
                                          (((kt3 * 4 + klane) ^ sw7) * 8));
            #pragma unroll
            for (int nf = 0; nf < 2; ++nf) {
                const int row = wn3 * 32 + nf * 16 + cl;
                bf3[nf] = *(const bf16x8*)(sl3 + row * 32 +
                                           ((klane ^ ((row + (row >> 2)) & 3)) * 8));
            }
            if (p3 + 2 < 128) stage3(p3 + 2);
            __builtin_amdgcn_s_setprio(1);
            #pragma unroll
            for (int mf = 0; mf < 2; ++mf)
                #pragma unroll
                for (int nf = 0; nf < 2; ++nf)
                    acc3[nc3][mf][nf] = __builtin_amdgcn_mfma_f32_16x16x32_bf16(
                        a3[mf], bf3[nf], acc3[nc3][mf][nf], 0, 0, 0);
            __builtin_amdgcn_s_setprio(0);
            WAITL0(); __builtin_amdgcn_sched_barrier(0);
            if (p3 + 2 < 128) { WAITV(1); } else { WAITV(0); }
            __builtin_amdgcn_s_barrier(); FENCE();
        }
    }

    // =================== coupling epilogue =================================
    #pragma unroll
    for (int nc3 = 0; nc3 < 4; ++nc3)
        #pragma unroll
        for (int mf = 0; mf < 2; ++mf)
            #pragma unroll
            for (int nf = 0; nf < 2; ++nf) {
                const int n = nc3 * 128 + wn3 * 32 + nf * 16 + cl;
                #pragma unroll
                for (int rr = 0; rr < 4; ++rr) {
                    const int m = m0 + wm3 * 32 + mf * 16 + rg + rr;
                    const float t = acc3[nc3][mf][nf][rr] + b3v[nc3][nf];
                    const int64_t p = (int64_t)m * IN_DIM + 2 * n;
                    float2 xv = *reinterpret_cast<const float2*>(&X[p]);
                    float2 o;
                    o.x = xv.x;          // even column: exact copy
                    o.y = xv.y + t;      // odd column: x + translation
                    *reinterpret_cast<float2*>(&Y[p]) = o;
                }
            }
}

// ---------------------------------------------------------------------------
extern "C" void kernel_launch(void* const* d_in, const int* in_sizes, int n_in,
                              void* d_out, int out_size, void* d_ws, size_t ws_size,
                              hipStream_t stream) {
    const float* x  = (const float*)d_in[0];
    const float* W1 = (const float*)d_in[1];
    const float* b1 = (const float*)d_in[2];
    const float* W2 = (const float*)d_in[3];
    const float* b2 = (const float*)d_in[4];
    const float* W3 = (const float*)d_in[5];
    const float* b3 = (const float*)d_in[6];
    float* y = (float*)d_out;

    char* ws = (char*)d_ws;
    u16* xm  = (u16*)(ws);                               // 64 MB
    u16* W1t = (u16*)(ws + 67108864);                    // 1 MB  [1024][512]
    u16* W2t = (u16*)(ws + 67108864 + 1048576);          // 2 MB  [1024][1024]
    u16* W3t = (u16*)(ws + 67108864 + 1048576 + 2097152);// 1 MB  [512][1024]

    prep_xm<<<BATCH * IN_DIM / 8 / 256, 256, 0, stream>>>(x, xm);

    wconv<<<(MASKED / 32) * (HIDDEN / 32), 256, 0, stream>>>(W1, W1t, MASKED, HIDDEN);
    wconv<<<(HIDDEN / 32) * (HIDDEN / 32), 256, 0, stream>>>(W2, W2t, HIDDEN, HIDDEN);
    wconv<<<(HIDDEN / 32) * ((IN_DIM - MASKED) / 32), 256, 0, stream>>>(W3, W3t, HIDDEN, IN_DIM - MASKED);

    mlp_fused<<<BATCH / 64, 512, 0, stream>>>(xm, W1t, W2t, W3t, b1, b2, b3, x, y);
}

// Round 7
// 443.141 us; speedup vs baseline: 1.3575x; 1.3575x over previous
//
#include <hip/hip_runtime.h>
#include <stdint.h>

#define BATCH  65536
#define IN_DIM 1024
#define MASKED 512
#define HIDDEN 1024

typedef unsigned short u16;
typedef __bf16 bf16x8 __attribute__((ext_vector_type(8)));
typedef float  f32x4  __attribute__((ext_vector_type(4)));

typedef __attribute__((address_space(1))) void gvoid;
typedef __attribute__((address_space(3))) void lvoid;

__device__ __forceinline__ u16 f32_to_bf16(float f) {
    union { float f; uint32_t u; } v; v.f = f;
    uint32_t r = v.u + 0x7FFFu + ((v.u >> 16) & 1u);   // round-to-nearest-even
    return (u16)(r >> 16);
}

// ---------------------------------------------------------------------------
// prep: x (BATCH x IN_DIM f32) -> xm (BATCH x MASKED bf16)  [even columns]
// ---------------------------------------------------------------------------
__global__ void prep_xm(const float* __restrict__ x, u16* __restrict__ xm) {
    int idx = blockIdx.x * blockDim.x + threadIdx.x;   // 0 .. BATCH*IN_DIM/8
    const float4* xv = reinterpret_cast<const float4*>(x);
    float4 v0 = xv[idx * 2];
    float4 v1 = xv[idx * 2 + 1];
    ushort4 o;
    o.x = f32_to_bf16(v0.x);
    o.y = f32_to_bf16(v0.z);
    o.z = f32_to_bf16(v1.x);
    o.w = f32_to_bf16(v1.z);
    reinterpret_cast<ushort4*>(xm)[idx] = o;
}

// ---------------------------------------------------------------------------
// weight convert+transpose: W (K x N f32, row-major) -> Wt (N x K bf16)
// ---------------------------------------------------------------------------
__global__ void wconv(const float* __restrict__ W, u16* __restrict__ Wt,
                      int K, int N) {
    __shared__ float t[32][33];
    const int nbk = K / 32;
    const int bk = blockIdx.x % nbk;
    const int bn = blockIdx.x / nbk;
    const int tx = threadIdx.x & 31;
    const int ty = threadIdx.x >> 5;   // 0..7
    const int k0 = bk * 32, n0 = bn * 32;
    #pragma unroll
    for (int i = 0; i < 4; ++i)
        t[ty + i * 8][tx] = W[(int64_t)(k0 + ty + i * 8) * N + n0 + tx];
    __syncthreads();
    #pragma unroll
    for (int i = 0; i < 4; ++i)
        Wt[(int64_t)(n0 + ty + i * 8) * K + k0 + tx] = f32_to_bf16(t[tx][ty + i * 8]);
}

// ---------------------------------------------------------------------------
// GEMM: C(MxN) = A(MxK,bf16) @ Bt(NxK,bf16)^T + bias
// MODE 0: C = relu(.) -> bf16 Cb
// MODE 1: coupling epilogue: y[m][2n] = x[m][2n]; y[m][2n+1] = x[m][2n+1] + t
// 128x128 tile, BK=64, 256 threads (4 waves, 2x2), mfma 16x16x32 bf16.
// T1 XCD swizzle. launch_bounds(256,4) (R1 lesson: (256,5) spills the acc).
//
// T2 chunk-XOR swizzle (R4-proven involution class, ported to BK=64):
//   LDS row holds its 8 16B-chunks permuted: lds_chunk c = global chunk
//   c ^ (row&7).  Write side: global_load_lds writes linearly, so the XOR is
//   applied to the per-lane GLOBAL source address (stays within the row's
//   128B -> coalescing intact).  Read side: fragment kcol chunk gets the same
//   XOR (row&7 == lane&7 for all fragment rows).  Result: each 16-lane
//   quarter of a ds_read_b128 hits 8 distinct 4-bank groups, 2 lanes each =
//   2-way = free (m136).  Without it: 16-way conflict, 5.03e7 cycles/dispatch
//   ~= 54% of G2's time (R2 counters).
// ---------------------------------------------------------------------------
template<int K, int N, int MODE>
__global__ __launch_bounds__(256, 4)
void gemm_bt(const u16* __restrict__ A, const u16* __restrict__ Bt,
             const float* __restrict__ bias,
             u16* __restrict__ Cb,
             const float* __restrict__ X,
             float* __restrict__ Y) {
    constexpr int BK = 64;
    __shared__ u16 As[128 * BK];
    __shared__ u16 Bs[128 * BK];

    const int tid  = threadIdx.x;
    const int lane = tid & 63;
    const int w    = tid >> 6;      // wave 0..3
    const int wr   = w >> 1;        // wave row (0..1)
    const int wc   = w & 1;         // wave col (0..1)

    // T1: XCD swizzle (grids here are all multiples of 8 -> bijective).
    const int nwg = gridDim.x;
    const int cpx = nwg >> 3;
    const int bid = (blockIdx.x & 7) * cpx + (blockIdx.x >> 3);

    constexpr int nbn = N / 128;
    const int bm = bid / nbn;
    const int bn = bid % nbn;
    const int m0 = bm * 128;
    const int n0 = bn * 128;

    f32x4 acc[4][4];
    #pragma unroll
    for (int i = 0; i < 4; ++i)
        #pragma unroll
        for (int j = 0; j < 4; ++j)
            acc[i][j] = f32x4{0.f, 0.f, 0.f, 0.f};

    // staging: wave w stages rows [w*32, w*32+32) in 4 calls of 8 rows each.
    // srow = lane>>3 (0..7): staged row = w*32 + c*8 + srow, so row&7 == srow.
    // T2 write side: source chunk = (lane&7) ^ srow.
    const int srow = lane >> 3;
    const int scol = ((lane & 7) ^ srow) * 8;
    const u16* aptr = A  + (int64_t)(m0 + w * 32 + srow) * K + scol;
    const u16* bptr = Bt + (int64_t)(n0 + w * 32 + srow) * K + scol;

    // T2 read side: fragment rows are base + (lane&15) with base%16==0, so
    // row&7 == lane&7.  Read chunk q = kk*4 + (lane>>4); LDS chunk = q^(lane&7).
    const int rxor = lane & 7;
    const int q0   = lane >> 4;            // 0..3

    for (int kt = 0; kt < K / BK; ++kt) {
        __syncthreads();   // previous tile fully consumed
        const int koff = kt * BK;
        #pragma unroll
        for (int c = 0; c < 4; ++c) {
            __builtin_amdgcn_global_load_lds(
                (gvoid*)(aptr + koff + c * 8 * K),
                (lvoid*)(&As[(w * 32 + c * 8) * BK]), 16, 0, 0);
            __builtin_amdgcn_global_load_lds(
                (gvoid*)(bptr + koff + c * 8 * K),
                (lvoid*)(&Bs[(w * 32 + c * 8) * BK]), 16, 0, 0);
        }
        __syncthreads();   // staged data visible (compiler drains vmcnt(0))

        #pragma unroll
        for (int kk = 0; kk < 2; ++kk) {
            const int kcol = ((kk * 4 + q0) ^ rxor) * 8;
            bf16x8 a[4], b[4];
            #pragma unroll
            for (int i = 0; i < 4; ++i)
                a[i] = *reinterpret_cast<const bf16x8*>(
                    &As[(wr * 64 + i * 16 + (lane & 15)) * BK + kcol]);
            #pragma unroll
            for (int j = 0; j < 4; ++j)
                b[j] = *reinterpret_cast<const bf16x8*>(
                    &Bs[(wc * 64 + j * 16 + (lane & 15)) * BK + kcol]);
            #pragma unroll
            for (int i = 0; i < 4; ++i)
                #pragma unroll
                for (int j = 0; j < 4; ++j)
                    acc[i][j] = __builtin_amdgcn_mfma_f32_16x16x32_bf16(
                        a[i], b[j], acc[i][j], 0, 0, 0);
        }
    }

    // epilogue. C/D layout (m89-verified): col = lane&15, row = (lane>>4)*4 + reg
    const int cl = lane & 15;
    const int rg = (lane >> 4) * 4;
    #pragma unroll
    for (int j = 0; j < 4; ++j) {
        const int n  = n0 + wc * 64 + j * 16 + cl;
        const float bv = bias[n];
        #pragma unroll
        for (int i = 0; i < 4; ++i) {
            #pragma unroll
            for (int r = 0; r < 4; ++r) {
                const int m = m0 + wr * 64 + i * 16 + rg + r;
                float v = acc[i][j][r] + bv;
                if (MODE == 0) {
                    v = v > 0.f ? v : 0.f;
                    Cb[(int64_t)m * N + n] = f32_to_bf16(v);
                } else {
                    const int64_t p = (int64_t)m * IN_DIM + 2 * n;
                    float2 xv = *reinterpret_cast<const float2*>(&X[p]);
                    float2 o;
                    o.x = xv.x;          // even column: exact copy
                    o.y = xv.y + v;      // odd column: x + translation
                    *reinterpret_cast<float2*>(&Y[p]) = o;
                }
            }
        }
    }
}

// ---------------------------------------------------------------------------
extern "C" void kernel_launch(void* const* d_in, const int* in_sizes, int n_in,
                              void* d_out, int out_size, void* d_ws, size_t ws_size,
                              hipStream_t stream) {
    const float* x  = (const float*)d_in[0];
    const float* W1 = (const float*)d_in[1];
    const float* b1 = (const float*)d_in[2];
    const float* W2 = (const float*)d_in[3];
    const float* b2 = (const float*)d_in[4];
    const float* W3 = (const float*)d_in[5];
    const float* b3 = (const float*)d_in[6];
    float* y = (float*)d_out;

    char* ws = (char*)d_ws;
    // layout: h1 (128MB) | h2 (128MB, first 64MB aliased by xm) | W1t|W2t|W3t
    u16* h1  = (u16*)(ws);
    u16* h2  = (u16*)(ws + 134217728);
    u16* xm  = (u16*)(ws + 134217728);                 // dead before h2 is written
    u16* W1t = (u16*)(ws + 268435456);
    u16* W2t = (u16*)(ws + 268435456 + 1048576);
    u16* W3t = (u16*)(ws + 268435456 + 1048576 + 2097152);

    // 1) extract even columns -> bf16
    prep_xm<<<BATCH * IN_DIM / 8 / 256, 256, 0, stream>>>(x, xm);

    // 2) convert + transpose weights to bf16 N x K
    wconv<<<(MASKED / 32) * (HIDDEN / 32), 256, 0, stream>>>(W1, W1t, MASKED, HIDDEN);
    wconv<<<(HIDDEN / 32) * (HIDDEN / 32), 256, 0, stream>>>(W2, W2t, HIDDEN, HIDDEN);
    wconv<<<(HIDDEN / 32) * ((IN_DIM - MASKED) / 32), 256, 0, stream>>>(W3, W3t, HIDDEN, IN_DIM - MASKED);

    // 3) three GEMMs
    gemm_bt<MASKED, HIDDEN, 0><<<(BATCH / 128) * (HIDDEN / 128), 256, 0, stream>>>(
        xm, W1t, b1, h1, nullptr, nullptr);
    gemm_bt<HIDDEN, HIDDEN, 0><<<(BATCH / 128) * (HIDDEN / 128), 256, 0, stream>>>(
        h1, W2t, b2, h2, nullptr, nullptr);
    gemm_bt<HIDDEN, IN_DIM - MASKED, 1><<<(BATCH / 128) * ((IN_DIM - MASKED) / 128), 256, 0, stream>>>(
        h2, W3t, b3, nullptr, x, y);
}